// Round 5
// baseline (182.719 us; speedup 1.0000x reference)
//
#include <hip/hip_runtime.h>
#include <math.h>

// Problem constants (from reference setup_inputs)
#define L0      3072
#define DIM     128
#define BATCH   1024
#define NNEG    512

// -------- workspace layout --------
// X0 : bf16[393216]              (feat @ w_self_0, bf16)
// Y0 : bf16[393216]              (feat @ w_neigh_0, bf16)   = X0 + 393216 elems
// H  : float @ 393216  (3072*512)  [A,B | C,D] layer-1 inputs
// R  : float @ 1966080 (3072*256)  layer-1 output, normalized
// aff: float @ 2752512 (1024)
// spPos @ 2753536, spNeg @ 2753537, rank @ 2753538 (1024 ints)

__device__ __forceinline__ float bf2f(unsigned short u) {
  return __uint_as_float(((unsigned)u) << 16);
}
__device__ __forceinline__ void store_out(float v, float* p) { *p = v; }
__device__ __forceinline__ void store_out(float v, unsigned short* p) {
  unsigned x = __float_as_uint(v);                 // f32 -> bf16 RNE
  *p = (unsigned short)((x + 0x7fff + ((x >> 16) & 1)) >> 16);
}

// Half-split matmul, 6 rows x 256 cols per 256-thread block (grid 512).
// A-tile in LDS (ds_read_b128 broadcast); W via coalesced global loads.
// No manual pipelining — partial unroll lets the compiler software-pipeline
// with fine-grained waitcnts (manual reg double-buffer forced full drains).
template<int K, int AW, int HOFF, bool NORM, typename OutT>
__global__ __launch_bounds__(256) void k_mm(
    const float* __restrict__ Ain,
    const float* __restrict__ W0, const float* __restrict__ W1,
    OutT* __restrict__ Out, const int ldo, const int outHalfOff,
    float* __restrict__ zbuf, const int zcount) {
  __shared__ float AT[6 * AW];
  __shared__ float rs[4][3];
  const int t = threadIdx.x;
  if (zbuf != nullptr && blockIdx.x == 0)
    for (int z = t; z < zcount; z += 256) zbuf[z] = 0.f;
  const int base = blockIdx.x * 6;
  {
    const float4* __restrict__ src = (const float4*)(Ain + base * AW);
    float4* __restrict__ dst = (float4*)AT;
    for (int idx = t; idx < 6 * AW / 4; idx += 256) dst[idx] = src[idx];
  }
  __syncthreads();

  const int half = t >> 7;              // wave-uniform
  const int rg = ((t >> 6) & 1) * 3;    // wave parity -> rows 0..2 / 3..5
  const int c = t & 63;
  const float* __restrict__ W = (half ? W1 : W0) + c;
  const float* __restrict__ A0 = AT + rg * AW + half * HOFF;

  float acc[3][2];
#pragma unroll
  for (int r = 0; r < 3; ++r) { acc[r][0] = 0.f; acc[r][1] = 0.f; }

#pragma unroll 4
  for (int d = 0; d < K; d += 4) {
    float4 a[3];
#pragma unroll
    for (int r = 0; r < 3; ++r) a[r] = *(const float4*)&A0[r * AW + d];
    float w0[4], w1[4];
#pragma unroll
    for (int i2 = 0; i2 < 4; ++i2) {
      w0[i2] = W[(d + i2) * 128];
      w1[i2] = W[(d + i2) * 128 + 64];
    }
#pragma unroll
    for (int i2 = 0; i2 < 4; ++i2)
#pragma unroll
      for (int r = 0; r < 3; ++r) {
        const float av = ((const float*)&a[r])[i2];
        acc[r][0] = fmaf(av, w0[i2], acc[r][0]);
        acc[r][1] = fmaf(av, w1[i2], acc[r][1]);
      }
  }

  float scale[3] = {1.f, 1.f, 1.f};
  if (NORM) {
    float p[3];
#pragma unroll
    for (int r = 0; r < 3; ++r) p[r] = acc[r][0] * acc[r][0] + acc[r][1] * acc[r][1];
#pragma unroll
    for (int off = 32; off > 0; off >>= 1)
#pragma unroll
      for (int r = 0; r < 3; ++r) p[r] += __shfl_xor(p[r], off, 64);
    const int wv = t >> 6;
    if ((t & 63) == 0) { rs[wv][0] = p[0]; rs[wv][1] = p[1]; rs[wv][2] = p[2]; }
    __syncthreads();
#pragma unroll
    for (int r = 0; r < 3; ++r) {
      const float s = (rg == 0) ? (rs[0][r] + rs[2][r]) : (rs[1][r] + rs[3][r]);
      scale[r] = rsqrtf(fmaxf(s, 1e-12f));
    }
  }
  OutT* __restrict__ O = Out + half * outHalfOff + c;
#pragma unroll
  for (int r = 0; r < 3; ++r) {
    store_out(acc[r][0] * scale[r], &O[(base + rg + r) * ldo]);
    store_out(acc[r][1] * scale[r], &O[(base + rg + r) * ldo + 64]);
  }
}

// Fused layer-0 + layer-1 aggregation, bf16 gathers. 640 threads = 10 waves;
// wave j owns hop-row j. Lane: c8 = lam&15 (8-col slot), sub = lam>>4 (row
// stride-4 partition of the 25 nb2 rows). Sub-partials combined intra-wave
// via shfl_xor (relu needs the full 25-sum). TWO barriers total.
// H[i] = [A,B | C,D]:
//   A[c] = relu(X0[nb0[i]][c])
//   B[c] = relu(0.1 * sum10_j Y0[nb1[10i+j]][c])
//   C[c] = 0.1 * sum10_j relu(X0[nb1[10i+j]][c])
//   D[c] = 0.1 * sum10_j relu(0.04 * sum25_k Y0[nb2[(10i+j)*25+k]][c])
__global__ __launch_bounds__(640) void k_aggregate(
    const unsigned short* __restrict__ X0, const unsigned short* __restrict__ Y0,
    const int* __restrict__ nb0, const int* __restrict__ nb1,
    const int* __restrict__ nb2, float* __restrict__ H) {
  __shared__ int idxs[260];                 // [0..249] nb2, [250..259] nb1
  __shared__ float gB[10][128], gC[10][128], gD[10][128];
  const int i = blockIdx.x;
  const int t = threadIdx.x;
  if (t < 250) idxs[t] = nb2[i * 250 + t];
  else if (t < 260) idxs[t] = nb1[i * 10 + t - 250];
  __syncthreads();

  const int j = t >> 6;                     // wave index = hop row j
  const int lam = t & 63;
  const int c8 = lam & 15;                  // cols 8*c8 .. 8*c8+7
  const int sub = lam >> 4;                 // 0..3
  const int* __restrict__ pj = idxs + j * 25;

  float d8[8];
#pragma unroll
  for (int e = 0; e < 8; ++e) d8[e] = 0.f;
#pragma unroll
  for (int m = 0; m < 7; ++m) {
    const int k = sub + 4 * m;
    if (k < 25) {
      const int r = pj[k];
      const float4 raw = *(const float4*)(Y0 + r * 128 + c8 * 8);  // 8 bf16
      const unsigned short* u = (const unsigned short*)&raw;
#pragma unroll
      for (int e = 0; e < 8; ++e) d8[e] += bf2f(u[e]);
    }
  }
#pragma unroll
  for (int e = 0; e < 8; ++e) d8[e] += __shfl_xor(d8[e], 16, 64);
#pragma unroll
  for (int e = 0; e < 8; ++e) d8[e] += __shfl_xor(d8[e], 32, 64);

  const int r1 = idxs[250 + j];
  if (sub == 0) {
#pragma unroll
    for (int e = 0; e < 8; ++e) gD[j][c8 * 8 + e] = fmaxf(d8[e] * 0.04f, 0.f);
    const float4 raw = *(const float4*)(Y0 + r1 * 128 + c8 * 8);
    const unsigned short* u = (const unsigned short*)&raw;
#pragma unroll
    for (int e = 0; e < 8; ++e) gB[j][c8 * 8 + e] = bf2f(u[e]);
  } else if (sub == 1) {
    const float4 raw = *(const float4*)(X0 + r1 * 128 + c8 * 8);
    const unsigned short* u = (const unsigned short*)&raw;
#pragma unroll
    for (int e = 0; e < 8; ++e) gC[j][c8 * 8 + e] = fmaxf(bf2f(u[e]), 0.f);
  }
  __syncthreads();

  if (t < 512) {
    const int q = t >> 7, c = t & 127;
    float v;
    if (q == 0) {
      v = fmaxf(bf2f(X0[nb0[i] * 128 + c]), 0.f);
    } else {
      const float* g = (q == 1) ? &gB[0][0] : (q == 2) ? &gC[0][0] : &gD[0][0];
      float s = 0.f;
#pragma unroll
      for (int jj = 0; jj < 10; ++jj) s += g[jj * 128 + c];
      v = s * 0.1f;
      if (q == 1) v = fmaxf(v, 0.f);
    }
    H[i * 512 + t] = v;
  }
}

__device__ __forceinline__ float softplusf(float x) {
  return fmaxf(x, 0.f) + log1pf(expf(-fabsf(x)));
}

// One block per b: 64 lanes stage src/pos rows to LDS (and write src_emb to
// d_out — srccopy fused); lane 0 runs the EXACT sequential fmaf chain
// d=0..255 (identical op order to k_neg — exact-tie reproduction for MRR).
__global__ __launch_bounds__(64) void k_aff(
    const float* __restrict__ O, const int* __restrict__ src_idx,
    const int* __restrict__ pos_idx, float* __restrict__ out_src,
    float* __restrict__ aff, float* __restrict__ spPos) {
  __shared__ float4 sv[64], pv[64];
  const int b = blockIdx.x;
  const int q = threadIdx.x;
  const int s = src_idx[b];
  const int p = pos_idx[b];
  float4 vs = ((const float4*)O)[s * 64 + q];
  ((float4*)out_src)[b * 64 + q] = vs;
  sv[q] = vs;
  pv[q] = ((const float4*)O)[p * 64 + q];
  __syncthreads();
  if (q == 0) {
    const float* __restrict__ ss = (const float*)sv;
    const float* __restrict__ pp = (const float*)pv;
    float a = 0.f;
#pragma unroll 16
    for (int d = 0; d < 256; ++d) a = fmaf(ss[d], pp[d], a);
    aff[b] = a;
    atomicAdd(spPos, softplusf(-a));
  }
}

// neg_aff tile (32 src rows x 64 neg cols per block): softplus sum and
// per-row rank counts (neg_aff >= aff; ties count — positive sorts last in
// the reference's stable double-argsort). Chain order per (r,c): d=0..255.
__global__ __launch_bounds__(256) void k_neg(
    const float* __restrict__ O, const int* __restrict__ src_idx,
    const int* __restrict__ neg_idx, const float* __restrict__ aff,
    int* __restrict__ rank, float* __restrict__ spNeg) {
  __shared__ float SL[32][129];
  __shared__ float NL[64][129];
  __shared__ float affL[32];
  __shared__ int cntL[32];
  const int t = threadIdx.x;
  const int rowBase = (blockIdx.x >> 3) * 32;
  const int colBase = (blockIdx.x & 7) * 64;
  if (t < 32) { affL[t] = aff[rowBase + t]; cntL[t] = 0; }
  const int ct = t & 31;
  const int rt = t >> 5;
  float acc[4][2];
#pragma unroll
  for (int k = 0; k < 4; ++k) { acc[k][0] = 0.f; acc[k][1] = 0.f; }
  for (int ch = 0; ch < 2; ++ch) {
    __syncthreads();
    for (int idx = t; idx < 32 * 128; idx += 256) {
      int r = idx >> 7, dd = idx & 127;
      SL[r][dd] = O[src_idx[rowBase + r] * 256 + ch * 128 + dd];
    }
    for (int idx = t; idx < 64 * 128; idx += 256) {
      int cpos = idx >> 7, dd = idx & 127;
      NL[cpos][dd] = O[neg_idx[colBase + cpos] * 256 + ch * 128 + dd];
    }
    __syncthreads();
    for (int dd = 0; dd < 128; ++dd) {
      float n0 = NL[ct][dd], n1 = NL[ct + 32][dd];
#pragma unroll
      for (int k = 0; k < 4; ++k) {
        float sv = SL[rt + 8 * k][dd];
        acc[k][0] = fmaf(sv, n0, acc[k][0]);
        acc[k][1] = fmaf(sv, n1, acc[k][1]);
      }
    }
  }
  float sp = 0.f;
#pragma unroll
  for (int k = 0; k < 4; ++k) {
    float a = affL[rt + 8 * k];
    int cnt = 0;
#pragma unroll
    for (int cc = 0; cc < 2; ++cc) {
      float v = acc[k][cc];
      sp += softplusf(v);
      cnt += (v >= a) ? 1 : 0;
    }
    if (cnt) atomicAdd(&cntL[rt + 8 * k], cnt);
  }
#pragma unroll
  for (int off = 32; off > 0; off >>= 1) sp += __shfl_down(sp, off, 64);
  if ((t & 63) == 0) atomicAdd(spNeg, sp);
  __syncthreads();
  if (t < 32) atomicAdd(&rank[rowBase + t], cntL[t]);
}

// mrr + loss scalars.
__global__ __launch_bounds__(256) void k_finalize(
    const int* __restrict__ rank, const float* __restrict__ spPos,
    const float* __restrict__ spNeg, float* __restrict__ out) {
  const int t = threadIdx.x;
  float s = 0.f;
  for (int i = t; i < BATCH; i += 256) s += 1.f / (float)(rank[i] + 1);
#pragma unroll
  for (int off = 32; off > 0; off >>= 1) s += __shfl_down(s, off, 64);
  __shared__ float wsum[4];
  if ((t & 63) == 0) wsum[t >> 6] = s;
  __syncthreads();
  if (t == 0) {
    float mrr = (wsum[0] + wsum[1] + wsum[2] + wsum[3]) * (1.f / 1024.f);
    float loss = (spPos[0] + spNeg[0]) * (1.f / 1024.f);
    out[BATCH * 256]     = loss;
    out[BATCH * 256 + 1] = mrr;
  }
}

extern "C" void kernel_launch(void* const* d_in, const int* in_sizes, int n_in,
                              void* d_out, int out_size, void* d_ws, size_t ws_size,
                              hipStream_t stream) {
  const float* feat   = (const float*)d_in[1];
  const int* src_idx  = (const int*)d_in[2];
  const int* pos_idx  = (const int*)d_in[3];
  const int* neg_idx  = (const int*)d_in[4];
  const int* nb0      = (const int*)d_in[5];
  const int* nb1      = (const int*)d_in[6];
  const int* nb2      = (const int*)d_in[7];
  const float* ws0    = (const float*)d_in[8];
  const float* wn0    = (const float*)d_in[9];
  const float* ws1    = (const float*)d_in[10];
  const float* wn1    = (const float*)d_in[11];

  float* wsf = (float*)d_ws;
  unsigned short* X0 = (unsigned short*)d_ws;       // bf16[393216]
  unsigned short* Y0 = X0 + 393216;                 // bf16[393216]
  float* H     = wsf + 393216;                      // 3072*512
  float* R     = wsf + 1966080;                     // 3072*256
  float* aff   = wsf + 2752512;
  float* spPos = wsf + 2753536;
  float* spNeg = wsf + 2753537;
  int*   rank  = (int*)(wsf + 2753538);
  float* out   = (float*)d_out;

  // X0 = bf16(feat@ws0), Y0 = bf16(feat@wn0); block 0 zeroes spPos/spNeg/rank
  k_mm<128, 128, 0, false, unsigned short><<<L0 / 6, 256, 0, stream>>>(
      feat, ws0, wn0, X0, 128, 393216, spPos, 1026);
  k_aggregate<<<L0, 640, 0, stream>>>(X0, Y0, nb0, nb1, nb2, H);
  // R[:, :128] = H[:, :256]@ws1 ; R[:, 128:] = H[:, 256:]@wn1 ; + L2-norm
  k_mm<256, 512, 256, true, float><<<L0 / 6, 256, 0, stream>>>(
      H, ws1, wn1, R, 256, 128, nullptr, 0);
  k_aff<<<BATCH, 64, 0, stream>>>(R, src_idx, pos_idx, out, aff, spPos);
  k_neg<<<(BATCH / 32) * (NNEG / 64), 256, 0, stream>>>(R, src_idx, neg_idx, aff, rank, spNeg);
  k_finalize<<<1, 256, 0, stream>>>(rank, spPos, spNeg, out);
}

// Round 6
// 165.433 us; speedup vs baseline: 1.1045x; 1.1045x over previous
//
#include <hip/hip_runtime.h>
#include <math.h>

// Problem constants (from reference setup_inputs)
#define L0      3072
#define BATCH   1024
#define NNEG    512

// -------- workspace layout --------
// X0 : bf16[393216]            (feat @ w_self_0, bf16)
// Y0 : bf16[393216]            = X0 + 393216 elems
// H  : float @ 393216 (3072*512)   [A,B | C,D] layer-1 inputs
// R  : float @ 1966080 (3072*256)  layer-1 output, normalized
// spPos @ 2752512, spNeg @ 2752513, rank @ 2752514 (1024 ints)

__device__ __forceinline__ float bf2f(unsigned short u) {
  return __uint_as_float(((unsigned)u) << 16);
}
__device__ __forceinline__ void store_out(float v, float* p) { *p = v; }
__device__ __forceinline__ void store_out(float v, unsigned short* p) {
  unsigned x = __float_as_uint(v);                 // f32 -> bf16 RNE
  *p = (unsigned short)((x + 0x7fff + ((x >> 16) & 1)) >> 16);
}

// Half-split matmul, 6 rows x 256 cols per 512-thread block (grid 512,
// 2 blocks/CU = 16 waves/CU). Wave w: half=w>>2, colg=(w>>1)&1, rowg=w&1.
// Thread = 3 rows x 1 col -> half the per-thread serial work of R5, 2x the
// wave-level overlap. A-tile in LDS (broadcast ds_read_b128); W coalesced
// from global; unroll-4 lets the compiler software-pipeline.
// NORM: fused row L2-normalization (mm2 only).
template<int K, int AW, int HOFF, bool NORM, typename OutT>
__global__ __launch_bounds__(512) void k_mm(
    const float* __restrict__ Ain,
    const float* __restrict__ W0, const float* __restrict__ W1,
    OutT* __restrict__ Out, const int ldo, const int outHalfOff,
    float* __restrict__ zbuf, const int zcount) {
  __shared__ float AT[6 * AW];
  __shared__ float rs[8][3];
  const int t = threadIdx.x;
  if (zbuf != nullptr && blockIdx.x == 0)
    for (int z = t; z < zcount; z += 512) zbuf[z] = 0.f;
  const int base = blockIdx.x * 6;
  {
    const float4* __restrict__ src = (const float4*)(Ain + base * AW);
    float4* __restrict__ dst = (float4*)AT;
    for (int idx = t; idx < 6 * AW / 4; idx += 512) dst[idx] = src[idx];
  }
  __syncthreads();

  const int wave = t >> 6;
  const int half = wave >> 2;
  const int colg = (wave >> 1) & 1;
  const int rowg = wave & 1;
  const int rg = rowg * 3;
  const int col = colg * 64 + (t & 63);
  const float* __restrict__ W = (half ? W1 : W0) + col;
  const float* __restrict__ A0 = AT + rg * AW + half * HOFF;

  float acc[3] = {0.f, 0.f, 0.f};
#pragma unroll 4
  for (int d = 0; d < K; d += 4) {
    float4 a[3];
#pragma unroll
    for (int r = 0; r < 3; ++r) a[r] = *(const float4*)&A0[r * AW + d];
    float w[4];
#pragma unroll
    for (int i2 = 0; i2 < 4; ++i2) w[i2] = W[(d + i2) * 128];
#pragma unroll
    for (int i2 = 0; i2 < 4; ++i2)
#pragma unroll
      for (int r = 0; r < 3; ++r)
        acc[r] = fmaf(((const float*)&a[r])[i2], w[i2], acc[r]);
  }

  float scale[3] = {1.f, 1.f, 1.f};
  if (NORM) {
    float p[3];
#pragma unroll
    for (int r = 0; r < 3; ++r) p[r] = acc[r] * acc[r];
#pragma unroll
    for (int off = 32; off > 0; off >>= 1)
#pragma unroll
      for (int r = 0; r < 3; ++r) p[r] += __shfl_xor(p[r], off, 64);
    if ((t & 63) == 0) { rs[wave][0] = p[0]; rs[wave][1] = p[1]; rs[wave][2] = p[2]; }
    __syncthreads();
#pragma unroll
    for (int r = 0; r < 3; ++r) {
      const float s = rs[rowg][r] + rs[rowg + 2][r] + rs[rowg + 4][r] + rs[rowg + 6][r];
      scale[r] = rsqrtf(fmaxf(s, 1e-12f));
    }
  }
  OutT* __restrict__ O = Out + half * outHalfOff;
#pragma unroll
  for (int r = 0; r < 3; ++r)
    store_out(acc[r] * scale[r], &O[(base + rg + r) * ldo + col]);
}

// Fused layer-0 + layer-1 aggregation, bf16 gathers, ONE barrier.
// 640 threads = 10 waves; wave j owns hop-row j. Lane lam: c8=lam&15 (8-col
// slot), sub=lam>>4 (stride-4 partition of the 25 nb2 rows). Indices: each
// lane<25 loads one nb2 index (single coalesced load), distributed in-loop
// via __shfl (no LDS stage, no barrier). Sub-partials combined via shfl_xor.
// H[i] = [A,B | C,D]:
//   A[c] = relu(X0[nb0[i]][c])
//   B[c] = relu(0.1 * sum10_j Y0[nb1[10i+j]][c])
//   C[c] = 0.1 * sum10_j relu(X0[nb1[10i+j]][c])
//   D[c] = 0.1 * sum10_j relu(0.04 * sum25_k Y0[nb2[(10i+j)*25+k]][c])
__global__ __launch_bounds__(640) void k_aggregate(
    const unsigned short* __restrict__ X0, const unsigned short* __restrict__ Y0,
    const int* __restrict__ nb0, const int* __restrict__ nb1,
    const int* __restrict__ nb2, float* __restrict__ H) {
  __shared__ float gB[10][128], gC[10][128], gD[10][128];
  const int i = blockIdx.x;
  const int t = threadIdx.x;
  const int n0 = nb0[i];                    // uniform s_load, in flight early
  const int j = t >> 6;                     // wave index = hop row j
  const int lam = t & 63;
  const int r = i * 10 + j;                 // wave-uniform
  int myidx = 0;
  if (lam < 25) myidx = nb2[r * 25 + lam];  // one coalesced 100B load/wave
  else if (lam == 25) myidx = nb1[r];
  const int c8 = lam & 15;
  const int sub = lam >> 4;

  float d8[8];
#pragma unroll
  for (int e = 0; e < 8; ++e) d8[e] = 0.f;
#pragma unroll
  for (int m = 0; m < 7; ++m) {
    const int k = sub + 4 * m;
    const int ridx = __shfl(myidx, k, 64);  // ds_bpermute distribute
    if (k < 25) {
      const float4 raw = *(const float4*)(Y0 + ridx * 128 + c8 * 8);  // 8 bf16
      const unsigned short* u = (const unsigned short*)&raw;
#pragma unroll
      for (int e = 0; e < 8; ++e) d8[e] += bf2f(u[e]);
    }
  }
#pragma unroll
  for (int e = 0; e < 8; ++e) d8[e] += __shfl_xor(d8[e], 16, 64);
#pragma unroll
  for (int e = 0; e < 8; ++e) d8[e] += __shfl_xor(d8[e], 32, 64);

  const int r1 = __shfl(myidx, 25, 64);
  if (sub == 0) {
#pragma unroll
    for (int e = 0; e < 8; ++e) gD[j][c8 * 8 + e] = fmaxf(d8[e] * 0.04f, 0.f);
    const float4 raw = *(const float4*)(Y0 + r1 * 128 + c8 * 8);
    const unsigned short* u = (const unsigned short*)&raw;
#pragma unroll
    for (int e = 0; e < 8; ++e) gB[j][c8 * 8 + e] = bf2f(u[e]);
  } else if (sub == 1) {
    const float4 raw = *(const float4*)(X0 + r1 * 128 + c8 * 8);
    const unsigned short* u = (const unsigned short*)&raw;
#pragma unroll
    for (int e = 0; e < 8; ++e) gC[j][c8 * 8 + e] = fmaxf(bf2f(u[e]), 0.f);
  }
  __syncthreads();

  if (t < 512) {
    const int q = t >> 7, c = t & 127;
    float v;
    if (q == 0) {
      v = fmaxf(bf2f(X0[n0 * 128 + c]), 0.f);
    } else {
      const float* g = (q == 1) ? &gB[0][0] : (q == 2) ? &gC[0][0] : &gD[0][0];
      float s = 0.f;
#pragma unroll
      for (int jj = 0; jj < 10; ++jj) s += g[jj * 128 + c];
      v = s * 0.1f;
      if (q == 1) v = fmaxf(v, 0.f);
    }
    H[i * 512 + t] = v;
  }
}

__device__ __forceinline__ float softplusf(float x) {
  return fmaxf(x, 0.f) + log1pf(expf(-fabsf(x)));
}

// neg_aff tile (32 src rows x 64 neg cols per block) with k_aff FUSED:
// each block recomputes its 32 aff values with the EXACT sequential fmaf
// chain d=0..255 (deterministic -> bit-identical across blocks; identical
// op order to the neg accumulator chains -> exact-tie reproduction for the
// reference's stable double-argsort, positive-last). colBase==0 blocks own
// spPos and the src_emb copy to d_out. rank += count(neg_aff >= aff).
__global__ __launch_bounds__(256) void k_neg(
    const float* __restrict__ O, const int* __restrict__ src_idx,
    const int* __restrict__ pos_idx, const int* __restrict__ neg_idx,
    float* __restrict__ out_src, int* __restrict__ rank,
    float* __restrict__ spPos, float* __restrict__ spNeg) {
  __shared__ float SL[32][129];
  __shared__ float NL[64][129];
  __shared__ float affL[32];
  __shared__ int cntL[32];
  const int t = threadIdx.x;
  const int rowBase = (blockIdx.x >> 3) * 32;
  const int colBase = (blockIdx.x & 7) * 64;
  const bool first = (colBase == 0);
  if (t < 32) {
    const int b = rowBase + t;
    const float* __restrict__ ps = O + src_idx[b] * 256;
    const float* __restrict__ pp = O + pos_idx[b] * 256;
    float a = 0.f;
#pragma unroll 16
    for (int d = 0; d < 256; ++d) a = fmaf(ps[d], pp[d], a);
    affL[t] = a;
    cntL[t] = 0;
    if (first) atomicAdd(spPos, softplusf(-a));
  }
  if (first) {  // src_emb copy (fused former k_srccopy/k_aff duty)
    for (int idx = t; idx < 32 * 64; idx += 256) {
      const int rr = idx >> 6, qq = idx & 63;
      ((float4*)out_src)[(rowBase + rr) * 64 + qq] =
          ((const float4*)O)[src_idx[rowBase + rr] * 64 + qq];
    }
  }
  const int ct = t & 31;
  const int rt = t >> 5;
  float acc[4][2];
#pragma unroll
  for (int k = 0; k < 4; ++k) { acc[k][0] = 0.f; acc[k][1] = 0.f; }
  for (int ch = 0; ch < 2; ++ch) {
    __syncthreads();
    for (int idx = t; idx < 32 * 128; idx += 256) {
      int r = idx >> 7, dd = idx & 127;
      SL[r][dd] = O[src_idx[rowBase + r] * 256 + ch * 128 + dd];
    }
    for (int idx = t; idx < 64 * 128; idx += 256) {
      int cpos = idx >> 7, dd = idx & 127;
      NL[cpos][dd] = O[neg_idx[colBase + cpos] * 256 + ch * 128 + dd];
    }
    __syncthreads();
    for (int dd = 0; dd < 128; ++dd) {
      float n0 = NL[ct][dd], n1 = NL[ct + 32][dd];
#pragma unroll
      for (int k = 0; k < 4; ++k) {
        float sv = SL[rt + 8 * k][dd];
        acc[k][0] = fmaf(sv, n0, acc[k][0]);
        acc[k][1] = fmaf(sv, n1, acc[k][1]);
      }
    }
  }
  float sp = 0.f;
#pragma unroll
  for (int k = 0; k < 4; ++k) {
    float a = affL[rt + 8 * k];
    int cnt = 0;
#pragma unroll
    for (int cc = 0; cc < 2; ++cc) {
      float v = acc[k][cc];
      sp += softplusf(v);
      cnt += (v >= a) ? 1 : 0;
    }
    if (cnt) atomicAdd(&cntL[rt + 8 * k], cnt);
  }
#pragma unroll
  for (int off = 32; off > 0; off >>= 1) sp += __shfl_down(sp, off, 64);
  if ((t & 63) == 0) atomicAdd(spNeg, sp);
  __syncthreads();
  if (t < 32) atomicAdd(&rank[rowBase + t], cntL[t]);
}

// mrr + loss scalars.
__global__ __launch_bounds__(256) void k_finalize(
    const int* __restrict__ rank, const float* __restrict__ spPos,
    const float* __restrict__ spNeg, float* __restrict__ out) {
  const int t = threadIdx.x;
  float s = 0.f;
  for (int i = t; i < BATCH; i += 256) s += 1.f / (float)(rank[i] + 1);
#pragma unroll
  for (int off = 32; off > 0; off >>= 1) s += __shfl_down(s, off, 64);
  __shared__ float wsum[4];
  if ((t & 63) == 0) wsum[t >> 6] = s;
  __syncthreads();
  if (t == 0) {
    float mrr = (wsum[0] + wsum[1] + wsum[2] + wsum[3]) * (1.f / 1024.f);
    float loss = (spPos[0] + spNeg[0]) * (1.f / 1024.f);
    out[BATCH * 256]     = loss;
    out[BATCH * 256 + 1] = mrr;
  }
}

extern "C" void kernel_launch(void* const* d_in, const int* in_sizes, int n_in,
                              void* d_out, int out_size, void* d_ws, size_t ws_size,
                              hipStream_t stream) {
  const float* feat   = (const float*)d_in[1];
  const int* src_idx  = (const int*)d_in[2];
  const int* pos_idx  = (const int*)d_in[3];
  const int* neg_idx  = (const int*)d_in[4];
  const int* nb0      = (const int*)d_in[5];
  const int* nb1      = (const int*)d_in[6];
  const int* nb2      = (const int*)d_in[7];
  const float* ws0    = (const float*)d_in[8];
  const float* wn0    = (const float*)d_in[9];
  const float* ws1    = (const float*)d_in[10];
  const float* wn1    = (const float*)d_in[11];

  float* wsf = (float*)d_ws;
  unsigned short* X0 = (unsigned short*)d_ws;       // bf16[393216]
  unsigned short* Y0 = X0 + 393216;                 // bf16[393216]
  float* H     = wsf + 393216;                      // 3072*512
  float* R     = wsf + 1966080;                     // 3072*256
  float* spPos = wsf + 2752512;
  float* spNeg = wsf + 2752513;
  int*   rank  = (int*)(wsf + 2752514);
  float* out   = (float*)d_out;

  // X0 = bf16(feat@ws0), Y0 = bf16(feat@wn0); block 0 zeroes spPos/spNeg/rank
  k_mm<128, 128, 0, false, unsigned short><<<L0 / 6, 512, 0, stream>>>(
      feat, ws0, wn0, X0, 128, 393216, spPos, 1026);
  k_aggregate<<<L0, 640, 0, stream>>>(X0, Y0, nb0, nb1, nb2, H);
  // R[:, :128] = H[:, :256]@ws1 ; R[:, 128:] = H[:, 256:]@wn1 ; + L2-norm
  k_mm<256, 512, 256, true, float><<<L0 / 6, 512, 0, stream>>>(
      H, ws1, wn1, R, 256, 128, nullptr, 0);
  k_neg<<<(BATCH / 32) * (NNEG / 64), 256, 0, stream>>>(
      R, src_idx, pos_idx, neg_idx, out, rank, spPos, spNeg);
  k_finalize<<<1, 256, 0, stream>>>(rank, spPos, spNeg, out);
}